// Round 2
// baseline (263.983 us; speedup 1.0000x reference)
//
#include <hip/hip_runtime.h>
#include <hip/hip_bf16.h>
#include <math.h>

#define N_NODES 1024
#define T_DIM 8
#define FO 64

__device__ __forceinline__ float readlane_f(float v, int l) {
    return __uint_as_float(__builtin_amdgcn_readlane(__float_as_uint(v), l));
}

// ---------------- Kernel A: h = inp @ W ; s1 = h@a1 ; s2 = h@a2 ----------------
// block = 256 threads, handles 4 rows n of one (b,t). grid = B*T*N/4 = 8192.
__global__ __launch_bounds__(256) void gat_h_kernel(
    const float* __restrict__ inp, const float* __restrict__ W,
    const float* __restrict__ a,
    float* __restrict__ hws, float* __restrict__ s1w, float* __restrict__ s2w)
{
    __shared__ float Wl[64 * 64];
    __shared__ float xl[4 * 64];

    const int tid  = threadIdx.x;
    const int nb   = blockIdx.x;          // 0..8191
    const int bt   = nb >> 8;             // 256 blocks per (b,t)
    const int n0   = (nb & 255) * 4;
    const int lane = tid & 63;            // = o
    const int nl   = tid >> 6;            // local row 0..3

    // stage W (4096 floats) via float4
    const float4* W4  = (const float4*)W;
    float4*       Wl4 = (float4*)Wl;
#pragma unroll
    for (int k = 0; k < 4; ++k) Wl4[tid + k * 256] = W4[tid + k * 256];
    // stage 4 input rows (256 floats)
    xl[tid] = inp[((size_t)bt * N_NODES + n0) * 64 + tid];
    __syncthreads();

    float hv = 0.f;
#pragma unroll
    for (int f = 0; f < 64; ++f)
        hv = fmaf(xl[nl * 64 + f], Wl[f * 64 + lane], hv);

    const int n = n0 + nl;
    hws[((size_t)bt * N_NODES + n) * 64 + lane] = hv;

    float v1 = hv * a[lane];
    float v2 = hv * a[64 + lane];
#pragma unroll
    for (int off = 32; off; off >>= 1) {
        v1 += __shfl_xor(v1, off, 64);
        v2 += __shfl_xor(v2, off, 64);
    }
    if (lane == 0) {
        s1w[bt * N_NODES + n] = v1;
        s2w[bt * N_NODES + n] = v2;
    }
}

// ---------------- Kernel B: fused scores + online softmax + PV + mask + ELU ----
// block = 256 (4 waves), i-tile = 64 rows (16 rows/wave), loop j in tiles of 64.
#define R_PER 16

__global__ __launch_bounds__(256) void gat_attn_kernel(
    const float* __restrict__ adj, const float* __restrict__ att_mask,
    const float* __restrict__ h, const float* __restrict__ s1w,
    const float* __restrict__ s2w, float* __restrict__ out)
{
    __shared__ float h_lds[64 * 64];   // j-major: h_lds[j*64+o]
    __shared__ float s2_lds[64];
    __shared__ float mj_lds[64];

    const int bt   = blockIdx.y;       // 0..31  (= b*8 + t)
    const int b    = bt >> 3;
    const int t    = bt & 7;
    const int i0   = blockIdx.x * 64;
    const int tid  = threadIdx.x;
    const int lane = tid & 63;
    const int wave = tid >> 6;
    const int irow0 = i0 + wave * R_PER;

    float acc[R_PER], lsum[R_PER], mrun[R_PER], s1v[R_PER];
#pragma unroll
    for (int r = 0; r < R_PER; ++r) {
        acc[r]  = 0.f;
        lsum[r] = 0.f;
        mrun[r] = -INFINITY;
        s1v[r]  = s1w[bt * N_NODES + irow0 + r];
    }

    const float* hbt  = h + (size_t)bt * N_NODES * 64;
    const float* adjt = adj + (size_t)t * N_NODES * N_NODES;

#pragma unroll 1
    for (int jt = 0; jt < N_NODES; jt += 64) {
        // ---- stage h tile (4096 floats) + s2 + mask_j ----
        const float4* hsrc = (const float4*)(hbt + (size_t)jt * 64);
        float4*       hdst = (float4*)h_lds;
#pragma unroll
        for (int k = 0; k < 4; ++k) hdst[tid + k * 256] = hsrc[tid + k * 256];
        if (tid < 64) {
            s2_lds[tid] = s2w[bt * N_NODES + jt + tid];
            mj_lds[tid] = att_mask[((size_t)b * N_NODES + jt + tid) * T_DIM + t];
        }
        __syncthreads();

#pragma unroll
        for (int rg = 0; rg < R_PER; rg += 4) {
            float pm[4];
#pragma unroll
            for (int k = 0; k < 4; ++k) {
                const int r = rg + k;
                const int i = irow0 + r;
                float adjv = adjt[(size_t)i * N_NODES + jt + lane];
                float e    = s1v[r] + s2_lds[lane];
                e = (e > 0.f) ? e : 0.2f * e;
                float att = (adjv > 0.f) ? e * adjv : -1e12f;

                float tmax = att;
#pragma unroll
                for (int off = 32; off; off >>= 1)
                    tmax = fmaxf(tmax, __shfl_xor(tmax, off, 64));
                float mn = fmaxf(mrun[r], tmax);
                float al = __expf(mrun[r] - mn);
                float p  = __expf(att - mn);
                float ps = p;
#pragma unroll
                for (int off = 32; off; off >>= 1)
                    ps += __shfl_xor(ps, off, 64);
                lsum[r] = lsum[r] * al + ps;
                mrun[r] = mn;
                acc[r] *= al;
                pm[k] = p * mj_lds[lane];   // fold m_j into PV weight
            }
            // ---- PV: acc[rg+k][o=lane] += sum_j pm[k][j] * h[j][o] ----
#pragma unroll
            for (int j2 = 0; j2 < 64; ++j2) {
                float hv = h_lds[j2 * 64 + lane];
#pragma unroll
                for (int k = 0; k < 4; ++k)
                    acc[rg + k] = fmaf(readlane_f(pm[k], j2), hv, acc[rg + k]);
            }
        }
        __syncthreads();
    }

    // ---- epilogue: * m_i / l, ELU, store ----
#pragma unroll
    for (int r = 0; r < R_PER; ++r) {
        const int i = irow0 + r;
        float mi = att_mask[((size_t)b * N_NODES + i) * T_DIM + t];
        float v  = mi * acc[r] / lsum[r];
        v = (v > 0.f) ? v : (__expf(v) - 1.f);
        out[((size_t)bt * N_NODES + i) * 64 + lane] = v;
    }
}

extern "C" void kernel_launch(void* const* d_in, const int* in_sizes, int n_in,
                              void* d_out, int out_size, void* d_ws, size_t ws_size,
                              hipStream_t stream) {
    (void)in_sizes; (void)n_in; (void)out_size; (void)ws_size;
    const float* adj      = (const float*)d_in[0];   // (T,N,N)
    const float* inp      = (const float*)d_in[1];   // (B,T,N,FI)
    const float* att_mask = (const float*)d_in[2];   // (B,N,T)
    const float* W        = (const float*)d_in[3];   // (FI,FO)
    const float* a        = (const float*)d_in[4];   // (2*FO,1)
    float* out = (float*)d_out;

    float* hws = (float*)d_ws;                       // B*T*N*FO   = 2M floats
    float* s1w = hws + (size_t)4 * 8 * 1024 * 64;    // B*T*N      = 32K floats
    float* s2w = s1w + (size_t)4 * 8 * 1024;

    gat_h_kernel<<<8192, 256, 0, stream>>>(inp, W, a, hws, s1w, s2w);
    dim3 grid(16, 32);
    gat_attn_kernel<<<grid, 256, 0, stream>>>(adj, att_mask, hws, s1w, s2w, out);
}

// Round 3
// 219.166 us; speedup vs baseline: 1.2045x; 1.2045x over previous
//
#include <hip/hip_runtime.h>
#include <hip/hip_bf16.h>
#include <math.h>

#define N_NODES 1024
#define T_DIM 8

typedef __bf16 bf16x8 __attribute__((ext_vector_type(8)));
typedef float  f32x4  __attribute__((ext_vector_type(4)));

__device__ __forceinline__ float readlane_f(float v, int l) {
    return __uint_as_float(__builtin_amdgcn_readlane(__float_as_uint(v), l));
}

// ---------------- Kernel A: h = inp@W ; s1,s2 ; write hT (bf16, [bt][o][n]) ---
// 512 blocks x 256 thr; block = one (bt, 64-row chunk). Wave handles 16 rows.
// Inner loop: 1 LDS read (W) + 4 readlane + 4 FMA per f (VALU-bound, not LDS).
__global__ __launch_bounds__(256) void gat_h_kernel(
    const float* __restrict__ inp, const float* __restrict__ W,
    const float* __restrict__ a,
    __bf16* __restrict__ hT, float* __restrict__ s1w, float* __restrict__ s2w)
{
    __shared__ float Wl[64 * 64];
    __shared__ float xl[64 * 64];
    __shared__ __bf16 htl[64 * 66];   // [o][row], stride 66 -> conflict-free transpose

    const int tid  = threadIdx.x;
    const int blk  = blockIdx.x;
    const int bt   = blk >> 4;
    const int n0   = (blk & 15) * 64;
    const int lane = tid & 63;        // = o in compute phase
    const int wave = tid >> 6;

    const float4* W4  = (const float4*)W;
    float4*       Wl4 = (float4*)Wl;
    const float4* x4  = (const float4*)(inp + (size_t)(bt * N_NODES + n0) * 64);
    float4*       xl4 = (float4*)xl;
#pragma unroll
    for (int k = 0; k < 4; ++k) {
        Wl4[tid + k * 256] = W4[tid + k * 256];
        xl4[tid + k * 256] = x4[tid + k * 256];
    }
    const float a1 = a[lane];
    const float a2 = a[64 + lane];
    __syncthreads();

#pragma unroll 1
    for (int rg = 0; rg < 16; rg += 4) {
        float xr[4], acc[4];
#pragma unroll
        for (int q = 0; q < 4; ++q) {
            xr[q]  = xl[(wave * 16 + rg + q) * 64 + lane];
            acc[q] = 0.f;
        }
#pragma unroll
        for (int f = 0; f < 64; ++f) {
            float w = Wl[f * 64 + lane];
#pragma unroll
            for (int q = 0; q < 4; ++q)
                acc[q] = fmaf(readlane_f(xr[q], f), w, acc[q]);
        }
#pragma unroll
        for (int q = 0; q < 4; ++q) {
            const int r = wave * 16 + rg + q;   // local row
            float v1 = acc[q] * a1, v2 = acc[q] * a2;
#pragma unroll
            for (int off = 32; off; off >>= 1) {
                v1 += __shfl_xor(v1, off, 64);
                v2 += __shfl_xor(v2, off, 64);
            }
            if (lane == 0) {
                s1w[bt * N_NODES + n0 + r] = v1;
                s2w[bt * N_NODES + n0 + r] = v2;
            }
            htl[lane * 66 + r] = (__bf16)acc[q];
        }
    }
    __syncthreads();

    // write hT[bt][o][n0+r0 .. +16] coalesced (thread: o = tid>>2, r0 = (tid&3)*16)
    {
        const int o  = tid >> 2;
        const int r0 = (tid & 3) * 16;
        unsigned u[8];
#pragma unroll
        for (int k = 0; k < 8; ++k)
            u[k] = *(const unsigned*)&htl[o * 66 + r0 + 2 * k];
        uint4* dst = (uint4*)(hT + (size_t)(bt * 64 + o) * N_NODES + n0 + r0);
        dst[0] = make_uint4(u[0], u[1], u[2], u[3]);
        dst[1] = make_uint4(u[4], u[5], u[6], u[7]);
    }
}

// ---------------- Kernel B: scores + softmax(no-max) + MFMA PV + mask + ELU ----
// grid (16 i-tiles, 32 bt) x 256 thr (4 waves x 16 rows).
// Scores: leaky bounds att in [-6, ~16] -> exp never overflows; p=exp(att) raw,
// lsum reduced once at the end (no online rescaling).
// PV: P -> LDS (bf16, stride 72) -> A-frag; h staged swizzled via global_load_lds
// -> B-frag; acc in C/D layout (col=lane&15, row=quad*4+reg).
__global__ __launch_bounds__(256) void gat_attn_kernel(
    const float* __restrict__ adj, const float* __restrict__ att_mask,
    const __bf16* __restrict__ hT, const float* __restrict__ s1w,
    const float* __restrict__ s2w, float* __restrict__ out)
{
    __shared__ __align__(16) __bf16 ht_l[64 * 64];      // [o][(jb^(o&7))*8 + j0]
    __shared__ __align__(16) __bf16 p_l[4][16 * 72];    // per wave [row][j], pad 72
    __shared__ float s2l[N_NODES];
    __shared__ float mjl[N_NODES];

    const int bt   = blockIdx.y;
    const int b    = bt >> 3;
    const int t    = bt & 7;
    const int i0   = blockIdx.x * 64;
    const int tid  = threadIdx.x;
    const int lane = tid & 63;
    const int wave = tid >> 6;
    const int irow0 = i0 + wave * 16;

    for (int k = tid; k < N_NODES; k += 256) {
        s2l[k] = s2w[bt * N_NODES + k];
        mjl[k] = att_mask[((size_t)b * N_NODES + k) * T_DIM + t];
    }

    f32x4 acc[4];
#pragma unroll
    for (int nc = 0; nc < 4; ++nc) acc[nc] = (f32x4){0.f, 0.f, 0.f, 0.f};
    float lsum[16], s1v[16];
#pragma unroll
    for (int r = 0; r < 16; ++r) {
        lsum[r] = 0.f;
        s1v[r]  = s1w[bt * N_NODES + irow0 + r];
    }

    const float*  adjrow = adj + (size_t)t * N_NODES * N_NODES + (size_t)irow0 * N_NODES;
    const __bf16* hTbt   = hT + (size_t)bt * 64 * N_NODES;
    const int     jb8    = ((lane & 7) ^ (lane >> 3)) * 8;  // swizzled source j-block

    __syncthreads();

#pragma unroll 1
    for (int jt = 0; jt < N_NODES; jt += 64) {
        // async stage: 2 x global_load_lds(16B) per wave = full 64x64 bf16 tile
#pragma unroll
        for (int c = 0; c < 2; ++c) {
            const int o = wave * 16 + c * 8 + (lane >> 3);
            const __bf16* gp = hTbt + (size_t)o * N_NODES + jt + jb8;
            __bf16* lp = (__bf16*)ht_l + (wave * 2 + c) * 512;  // wave-uniform base
            __builtin_amdgcn_global_load_lds(
                (const __attribute__((address_space(1))) unsigned int*)gp,
                (__attribute__((address_space(3))) unsigned int*)lp,
                16, 0, 0);
        }

        // scores: lane = j within tile
        const float  s2v  = s2l[jt + lane];
        const float  mjv  = mjl[jt + lane];
        const float* arow = adjrow + jt + lane;
#pragma unroll
        for (int r = 0; r < 16; ++r) {
            float adjv = arow[(size_t)r * N_NODES];
            float e    = s1v[r] + s2v;
            e = (e > 0.f) ? e : 0.2f * e;
            float p = (adjv > 0.f) ? __expf(e * adjv) : 0.f;
            lsum[r] += p;
            p_l[wave][r * 72 + lane] = (__bf16)(p * mjv);
        }
        __syncthreads();   // drains global_load_lds (vmcnt) + p_l writes

        // acc[nc] += P(16x64) @ H(64 x 16nc)
#pragma unroll
        for (int kc = 0; kc < 2; ++kc) {
            bf16x8 af = *(const bf16x8*)&p_l[wave][(lane & 15) * 72 + kc * 32 + (lane >> 4) * 8];
#pragma unroll
            for (int nc = 0; nc < 4; ++nc) {
                const int o   = nc * 16 + (lane & 15);
                const int jb  = kc * 4 + (lane >> 4);
                const int pos = jb ^ (lane & 7);       // o&7 == lane&7
                bf16x8 bfr = *(const bf16x8*)&ht_l[o * 64 + pos * 8];
                acc[nc] = __builtin_amdgcn_mfma_f32_16x16x32_bf16(af, bfr, acc[nc], 0, 0, 0);
            }
        }
        __syncthreads();
    }

    // epilogue: one wave-reduction of lsum, then mi/ls scale + ELU + store
#pragma unroll
    for (int r = 0; r < 16; ++r) {
#pragma unroll
        for (int off = 32; off; off >>= 1)
            lsum[r] += __shfl_xor(lsum[r], off, 64);
    }
    const int q = lane >> 4;
#pragma unroll
    for (int reg = 0; reg < 4; ++reg) {
        float ls = (q == 0) ? lsum[reg] : (q == 1) ? lsum[4 + reg]
                 : (q == 2) ? lsum[8 + reg] : lsum[12 + reg];
        const int i = irow0 + q * 4 + reg;
        float mi    = att_mask[((size_t)b * N_NODES + i) * T_DIM + t];
        float scale = mi / ls;
#pragma unroll
        for (int nc = 0; nc < 4; ++nc) {
            float v = acc[nc][reg] * scale;
            v = (v > 0.f) ? v : (__expf(v) - 1.f);
            out[((size_t)bt * N_NODES + i) * 64 + nc * 16 + (lane & 15)] = v;
        }
    }
}

extern "C" void kernel_launch(void* const* d_in, const int* in_sizes, int n_in,
                              void* d_out, int out_size, void* d_ws, size_t ws_size,
                              hipStream_t stream) {
    (void)in_sizes; (void)n_in; (void)out_size; (void)ws_size;
    const float* adj      = (const float*)d_in[0];   // (T,N,N)
    const float* inp      = (const float*)d_in[1];   // (B,T,N,FI)
    const float* att_mask = (const float*)d_in[2];   // (B,N,T)
    const float* W        = (const float*)d_in[3];   // (FI,FO)
    const float* a        = (const float*)d_in[4];   // (2*FO,1)
    float* out = (float*)d_out;

    __bf16* hT  = (__bf16*)d_ws;                             // 32*64*1024 bf16 = 4 MB
    float*  s1w = (float*)((char*)d_ws + (size_t)4 * 1024 * 1024);
    float*  s2w = s1w + 32 * N_NODES;

    gat_h_kernel<<<512, 256, 0, stream>>>(inp, W, a, hT, s1w, s2w);
    dim3 grid(16, 32);
    gat_attn_kernel<<<grid, 256, 0, stream>>>(adj, att_mask, hT, s1w, s2w, out);
}

// Round 4
// 140.618 us; speedup vs baseline: 1.8773x; 1.5586x over previous
//
#include <hip/hip_runtime.h>
#include <hip/hip_bf16.h>
#include <math.h>

#define N_NODES 1024
#define T_DIM 8

typedef __bf16 bf16x8 __attribute__((ext_vector_type(8)));
typedef float  f32x4  __attribute__((ext_vector_type(4)));

__device__ __forceinline__ float readlane_f(float v, int l) {
    return __uint_as_float(__builtin_amdgcn_readlane(__float_as_uint(v), l));
}

// ---------------- Kernel A: h = inp@W ; s1,s2 ; write hT (bf16, [bt][o][n]) ---
// 512 blocks x 256 thr; block = one (bt, 64-row chunk). Wave handles 16 rows.
__global__ __launch_bounds__(256) void gat_h_kernel(
    const float* __restrict__ inp, const float* __restrict__ W,
    const float* __restrict__ a,
    __bf16* __restrict__ hT, float* __restrict__ s1w, float* __restrict__ s2w)
{
    __shared__ float Wl[64 * 64];
    __shared__ float xl[64 * 64];
    __shared__ __bf16 htl[64 * 66];   // [o][row], stride 66 -> conflict-free transpose

    const int tid  = threadIdx.x;
    const int blk  = blockIdx.x;
    const int bt   = blk >> 4;
    const int n0   = (blk & 15) * 64;
    const int lane = tid & 63;        // = o in compute phase
    const int wave = tid >> 6;

    const float4* W4  = (const float4*)W;
    float4*       Wl4 = (float4*)Wl;
    const float4* x4  = (const float4*)(inp + (size_t)(bt * N_NODES + n0) * 64);
    float4*       xl4 = (float4*)xl;
#pragma unroll
    for (int k = 0; k < 4; ++k) {
        Wl4[tid + k * 256] = W4[tid + k * 256];
        xl4[tid + k * 256] = x4[tid + k * 256];
    }
    const float a1 = a[lane];
    const float a2 = a[64 + lane];
    __syncthreads();

#pragma unroll 1
    for (int rg = 0; rg < 16; rg += 4) {
        float xr[4], acc[4];
#pragma unroll
        for (int q = 0; q < 4; ++q) {
            xr[q]  = xl[(wave * 16 + rg + q) * 64 + lane];
            acc[q] = 0.f;
        }
#pragma unroll
        for (int f = 0; f < 64; ++f) {
            float w = Wl[f * 64 + lane];
#pragma unroll
            for (int q = 0; q < 4; ++q)
                acc[q] = fmaf(readlane_f(xr[q], f), w, acc[q]);
        }
#pragma unroll
        for (int q = 0; q < 4; ++q) {
            const int r = wave * 16 + rg + q;   // local row
            float v1 = acc[q] * a1, v2 = acc[q] * a2;
#pragma unroll
            for (int off = 32; off; off >>= 1) {
                v1 += __shfl_xor(v1, off, 64);
                v2 += __shfl_xor(v2, off, 64);
            }
            if (lane == 0) {
                s1w[bt * N_NODES + n0 + r] = v1;
                s2w[bt * N_NODES + n0 + r] = v2;
            }
            htl[lane * 66 + r] = (__bf16)acc[q];
        }
    }
    __syncthreads();

    // write hT[bt][o][n0+r0..+16] coalesced (thread: o = tid>>2, r0 = (tid&3)*16)
    {
        const int o  = tid >> 2;
        const int r0 = (tid & 3) * 16;
        unsigned u[8];
#pragma unroll
        for (int k = 0; k < 8; ++k)
            u[k] = *(const unsigned*)&htl[o * 66 + r0 + 2 * k];
        uint4* dst = (uint4*)(hT + (size_t)(bt * 64 + o) * N_NODES + n0 + r0);
        dst[0] = make_uint4(u[0], u[1], u[2], u[3]);
        dst[1] = make_uint4(u[4], u[5], u[6], u[7]);
    }
}

// ---------------- Kernel B: barrier-free one-wave flash GAT ------------------
// grid (64 i-tiles, 32 bt) x 64 thr. Wave owns 16 rows, all 64 outputs.
// h B-frags read DIRECTLY from global hT (contiguous 16B = exact fragment);
// adj/s2/mask/h all register-prefetched one j-tile ahead. LDS = 2.3 KB P
// transpose buffer only (wave-private) => no __syncthreads anywhere.
// Scores: leaky bounds att ~[-6,16] => exp never overflows, no max pass;
// lsum accumulated per-lane, reduced once at the end.
__global__ __launch_bounds__(64) void gat_attn_kernel(
    const float* __restrict__ adj, const float* __restrict__ att_mask,
    const __bf16* __restrict__ hT, const float* __restrict__ s1w,
    const float* __restrict__ s2w, float* __restrict__ out)
{
    __shared__ __align__(16) __bf16 p_l[16 * 72];   // [row][j], pad 72

    const int bt    = blockIdx.y;
    const int b     = bt >> 3;
    const int t     = bt & 7;
    const int irow0 = blockIdx.x * 16;
    const int lane  = threadIdx.x;      // = j within tile

    f32x4 acc[4];
#pragma unroll
    for (int nc = 0; nc < 4; ++nc) acc[nc] = (f32x4){0.f, 0.f, 0.f, 0.f};
    float lsum[16], s1v[16];
#pragma unroll
    for (int r = 0; r < 16; ++r) {
        lsum[r] = 0.f;
        s1v[r]  = s1w[bt * N_NODES + irow0 + r];
    }

    const float*  adjrow = adj + (size_t)t * N_NODES * N_NODES
                               + (size_t)irow0 * N_NODES + lane;
    // per-lane h fragment base: row (lane&15), jb offset (lane>>4)*8
    const __bf16* hlane  = hT + (size_t)bt * 64 * N_NODES
                              + (size_t)(lane & 15) * N_NODES + (lane >> 4) * 8;
    const float*  s2bt   = s2w + bt * N_NODES;
    const float*  mbase  = att_mask + (size_t)b * N_NODES * T_DIM + t;
    __bf16* pwr = p_l + lane;                                  // score write slot
    const __bf16* prd = p_l + (lane & 15) * 72 + (lane >> 4) * 8;  // A-frag read

    // ---- preload tile 0 ----
    float  adjc[16];
    bf16x8 hc[8];
    float  s2c, mjc;
#pragma unroll
    for (int r = 0; r < 16; ++r) adjc[r] = adjrow[(size_t)r * N_NODES];
#pragma unroll
    for (int kc = 0; kc < 2; ++kc)
#pragma unroll
        for (int nc = 0; nc < 4; ++nc)
            hc[kc * 4 + nc] = *(const bf16x8*)(hlane + (size_t)nc * 16 * N_NODES + kc * 32);
    s2c = s2bt[lane];
    mjc = mbase[(size_t)lane * T_DIM];

#pragma unroll 2
    for (int it = 0; it < 16; ++it) {
        const int jn = (it < 15) ? (it + 1) * 64 : 0;   // next tile (wrap, unused at end)

        // ---- prefetch next tile into the shadow registers ----
        float  adjn[16];
        bf16x8 hn[8];
#pragma unroll
        for (int r = 0; r < 16; ++r) adjn[r] = adjrow[(size_t)r * N_NODES + jn];
#pragma unroll
        for (int kc = 0; kc < 2; ++kc)
#pragma unroll
            for (int nc = 0; nc < 4; ++nc)
                hn[kc * 4 + nc] = *(const bf16x8*)(hlane + (size_t)nc * 16 * N_NODES + jn + kc * 32);
        const float s2n = s2bt[jn + lane];
        const float mjn = mbase[(size_t)(jn + lane) * T_DIM];

        // ---- scores for current tile (lane = j) ----
#pragma unroll
        for (int r = 0; r < 16; ++r) {
            float e = s1v[r] + s2c;
            e = (e > 0.f) ? e : 0.2f * e;
            float p = (adjc[r] > 0.f) ? __expf(e * adjc[r]) : 0.f;
            lsum[r] += p;
            pwr[r * 72] = (__bf16)(p * mjc);
        }

        // ---- P -> A-frag via wave-private LDS, then 8 MFMAs ----
        bf16x8 af0 = *(const bf16x8*)(prd);
        bf16x8 af1 = *(const bf16x8*)(prd + 32);
#pragma unroll
        for (int nc = 0; nc < 4; ++nc)
            acc[nc] = __builtin_amdgcn_mfma_f32_16x16x32_bf16(af0, hc[nc], acc[nc], 0, 0, 0);
#pragma unroll
        for (int nc = 0; nc < 4; ++nc)
            acc[nc] = __builtin_amdgcn_mfma_f32_16x16x32_bf16(af1, hc[4 + nc], acc[nc], 0, 0, 0);

        // ---- rotate prefetch buffers (unroll-2 kills the movs) ----
#pragma unroll
        for (int r = 0; r < 16; ++r) adjc[r] = adjn[r];
#pragma unroll
        for (int k = 0; k < 8; ++k) hc[k] = hn[k];
        s2c = s2n;
        mjc = mjn;
    }

    // ---- epilogue: reduce lsum once, mi/ls scale + ELU + store ----
#pragma unroll
    for (int r = 0; r < 16; ++r) {
#pragma unroll
        for (int off = 32; off; off >>= 1)
            lsum[r] += __shfl_xor(lsum[r], off, 64);
    }
    const int q = lane >> 4;
#pragma unroll
    for (int reg = 0; reg < 4; ++reg) {
        float ls = (q == 0) ? lsum[reg] : (q == 1) ? lsum[4 + reg]
                 : (q == 2) ? lsum[8 + reg] : lsum[12 + reg];
        const int i = irow0 + q * 4 + reg;
        float mi    = att_mask[((size_t)b * N_NODES + i) * T_DIM + t];
        float scale = mi / ls;
#pragma unroll
        for (int nc = 0; nc < 4; ++nc) {
            float v = acc[nc][reg] * scale;
            v = (v > 0.f) ? v : (__expf(v) - 1.f);
            out[((size_t)bt * N_NODES + i) * 64 + nc * 16 + (lane & 15)] = v;
        }
    }
}

extern "C" void kernel_launch(void* const* d_in, const int* in_sizes, int n_in,
                              void* d_out, int out_size, void* d_ws, size_t ws_size,
                              hipStream_t stream) {
    (void)in_sizes; (void)n_in; (void)out_size; (void)ws_size;
    const float* adj      = (const float*)d_in[0];   // (T,N,N)
    const float* inp      = (const float*)d_in[1];   // (B,T,N,FI)
    const float* att_mask = (const float*)d_in[2];   // (B,N,T)
    const float* W        = (const float*)d_in[3];   // (FI,FO)
    const float* a        = (const float*)d_in[4];   // (2*FO,1)
    float* out = (float*)d_out;

    __bf16* hT  = (__bf16*)d_ws;                             // 32*64*1024 bf16 = 4 MB
    float*  s1w = (float*)((char*)d_ws + (size_t)4 * 1024 * 1024);
    float*  s2w = s1w + 32 * N_NODES;

    gat_h_kernel<<<512, 256, 0, stream>>>(inp, W, a, hT, s1w, s2w);
    dim3 grid(64, 32);
    gat_attn_kernel<<<grid, 64, 0, stream>>>(adj, att_mask, hT, s1w, s2w, out);
}